// Round 3
// baseline (1871.738 us; speedup 1.0000x reference)
//
#include <hip/hip_runtime.h>
#include <cstdint>

#define TTOK 8192
#define HID  1024
#define FFD  4096
#define NEXP 8
#define NASSIGN 16384   // TTOK * 2

typedef __attribute__((ext_vector_type(8))) short bf16x8;
typedef __attribute__((ext_vector_type(4))) float f32x4;

__device__ __forceinline__ unsigned short f2bf(float f) {
  unsigned int u = __builtin_bit_cast(unsigned int, f);
  u += 0x7FFFu + ((u >> 16) & 1u);           // RNE
  return (unsigned short)(u >> 16);
}

__device__ __forceinline__ void gload16(const unsigned short* g, unsigned short* l) {
  __builtin_amdgcn_global_load_lds(
      (const __attribute__((address_space(1))) unsigned int*)g,
      (__attribute__((address_space(3))) unsigned int*)l, 16, 0, 0);
}

// swizzled source column (elements) for staging thread t: slot ^= (row>>1)&3,
// row = t>>2 so (row>>1)&3 = (t>>3)&3. Involution; matched by read-side XOR.
__device__ __forceinline__ int swz_col(int t) {
  return (((t & 3) ^ ((t >> 3) & 3)) << 3);
}

// ---------------- routing ----------------

__global__ void zero_counts_kernel(int* counts) {
  if (threadIdx.x < NEXP) counts[threadIdx.x] = 0;
}

__global__ void gate_kernel(const float* __restrict__ x,
                            const float* __restrict__ gw,
                            const float* __restrict__ gb,
                            float* __restrict__ logits_out,
                            int* __restrict__ counts,
                            int* __restrict__ te, int* __restrict__ tp,
                            float* __restrict__ tw) {
  const int lane = threadIdx.x & 63;
  const int wib  = threadIdx.x >> 6;
  const int t = blockIdx.x * 4 + wib;
  const float* xr = x + (size_t)t * HID;

  float acc[NEXP];
#pragma unroll
  for (int e = 0; e < NEXP; ++e) acc[e] = 0.f;

#pragma unroll
  for (int i = 0; i < HID / 64; ++i) {
    int h = lane + 64 * i;
    float xv = xr[h];
    const float* g = gw + h * NEXP;
#pragma unroll
    for (int e = 0; e < NEXP; ++e) acc[e] += xv * g[e];
  }
#pragma unroll
  for (int off = 32; off; off >>= 1)
#pragma unroll
    for (int e = 0; e < NEXP; ++e) acc[e] += __shfl_xor(acc[e], off);
#pragma unroll
  for (int e = 0; e < NEXP; ++e) acc[e] += gb[e];

  if (lane < NEXP) logits_out[(size_t)t * NEXP + lane] = acc[lane];

  if (lane == 0) {
    int e0 = 0; float v0 = acc[0];
#pragma unroll
    for (int e = 1; e < NEXP; ++e) if (acc[e] > v0) { v0 = acc[e]; e0 = e; }
    int e1 = -1; float v1 = -3.4e38f;
#pragma unroll
    for (int e = 0; e < NEXP; ++e) if (e != e0 && acc[e] > v1) { v1 = acc[e]; e1 = e; }
    float s = __expf(v1 - v0);         // v1 <= v0
    float w0 = 1.f / (1.f + s);
    float w1 = s * w0;
    int p0 = atomicAdd(&counts[e0], 1);
    int p1 = atomicAdd(&counts[e1], 1);
    te[t * 2] = e0; te[t * 2 + 1] = e1;
    tp[t * 2] = p0; tp[t * 2 + 1] = p1;
    tw[t * 2] = w0; tw[t * 2 + 1] = w1;
  }
}

__global__ void scatter_kernel(const int* __restrict__ counts, int* __restrict__ offsets,
                               const int* __restrict__ te, const int* __restrict__ tp,
                               const float* __restrict__ tw,
                               int* __restrict__ tok_of, float* __restrict__ wt_of,
                               int* __restrict__ asn_of) {
  __shared__ int offs[NEXP];
  if (threadIdx.x == 0) {
    int run = 0;
    for (int e = 0; e < NEXP; ++e) { offs[e] = run; offsets[e] = run; run += counts[e]; }
  }
  __syncthreads();
  for (int t = threadIdx.x; t < TTOK; t += blockDim.x) {
#pragma unroll
    for (int j = 0; j < 2; ++j) {
      int e = te[t * 2 + j];
      int a = offs[e] + tp[t * 2 + j];
      tok_of[a] = t;
      wt_of[a] = tw[t * 2 + j];
      asn_of[t * 2 + j] = a;
    }
  }
}

// ---------------- dtype prep ----------------

__global__ void convert_x_kernel(const float* __restrict__ x, unsigned short* __restrict__ xb) {
  size_t i = ((size_t)blockIdx.x * 256 + threadIdx.x) * 8;
  float4 a = *(const float4*)(x + i);
  float4 b = *(const float4*)(x + i + 4);
  union { unsigned short us[8]; uint4 v; } u;
  u.us[0] = f2bf(a.x); u.us[1] = f2bf(a.y); u.us[2] = f2bf(a.z); u.us[3] = f2bf(a.w);
  u.us[4] = f2bf(b.x); u.us[5] = f2bf(b.y); u.us[6] = f2bf(b.z); u.us[7] = f2bf(b.w);
  *(uint4*)(xb + i) = u.v;
}

// src [z][R][C] fp32 -> dst [z][C][R] bf16
__global__ void transpose_cvt_kernel(const float* __restrict__ src,
                                     unsigned short* __restrict__ dst, int R, int C) {
  __shared__ float tile[32][33];
  const int r0 = blockIdx.y * 32, c0 = blockIdx.x * 32;
  const size_t base = (size_t)blockIdx.z * R * C;
  src += base; dst += base;
#pragma unroll
  for (int i = threadIdx.y; i < 32; i += 8)
    tile[i][threadIdx.x] = src[(size_t)(r0 + i) * C + c0 + threadIdx.x];
  __syncthreads();
#pragma unroll
  for (int i = threadIdx.y; i < 32; i += 8)
    dst[(size_t)(c0 + i) * R + r0 + threadIdx.x] = f2bf(tile[threadIdx.x][i]);
}

// ---------------- expert GEMMs ----------------
// Deep-pipelined (4-buffer ring, counted vmcnt, never drain-0 in loop),
// LDS XOR-swizzle via pre-swizzled global source + swizzled ds_read,
// s_setprio(1) around MFMA clusters. 512 threads / 8 waves / 1 block/CU.

#define UBM 256
#define UBN 128
#define BK  32
// up LDS elems per buffer: A 256*32=8192, Bg/Bu 128*32=4096

__global__ __launch_bounds__(512, 2) void moe_up_kernel(
    const unsigned short* __restrict__ xb,    // [T][H] bf16
    const unsigned short* __restrict__ WgT,   // [E][F][H] bf16
    const unsigned short* __restrict__ WuT,   // [E][F][H] bf16
    const int* __restrict__ counts, const int* __restrict__ offsets,
    const int* __restrict__ tok_of,
    unsigned short* __restrict__ hbuf)        // [A][F] bf16
{
  const int e = blockIdx.x >> 5;
  const int mblk = blockIdx.x & 31;
  const int cnt = counts[e];
  if (mblk * UBM >= cnt) return;
  const int off = offsets[e];
  const int n0 = blockIdx.y * UBN;

  __shared__ __align__(16) unsigned short As[4 * UBM * BK];    // 64 KiB
  __shared__ __align__(16) unsigned short Bgs[4 * UBN * BK];   // 32 KiB
  __shared__ __align__(16) unsigned short Bus[4 * UBN * BK];   // 32 KiB
  __shared__ int toks[UBM];

  const int tid = threadIdx.x;
  const int lane = tid & 63;
  const int w = tid >> 6;

  for (int i = tid; i < UBM; i += 512) {
    int a = off + mblk * UBM + i;
    if (a > NASSIGN - 1) a = NASSIGN - 1;
    toks[i] = tok_of[a];
  }
  __syncthreads();

  // staging source pointers (per thread, pre-swizzled column)
  const int trow = tid >> 2;
  const int tcol = swz_col(tid);
  const unsigned short* a_src0 = xb + (size_t)toks[trow] * HID + tcol;
  const unsigned short* a_src1 = xb + (size_t)toks[128 + trow] * HID + tcol;
  const unsigned short* bg_src = WgT + ((size_t)e * FFD + n0 + trow) * HID + tcol;
  const unsigned short* bu_src = WuT + ((size_t)e * FFD + n0 + trow) * HID + tcol;

  auto STAGE_A = [&](int kt) {
    const int b = kt & 3, k0 = kt * BK;
    gload16(a_src0 + k0, As + b * (UBM * BK) + tid * 8);
    gload16(a_src1 + k0, As + b * (UBM * BK) + 4096 + tid * 8);
  };
  auto STAGE_B = [&](int kt) {
    const int b = kt & 3, k0 = kt * BK;
    gload16(bg_src + k0, Bgs + b * (UBN * BK) + tid * 8);
    gload16(bu_src + k0, Bus + b * (UBN * BK) + tid * 8);
  };

  // read-side constants: XOR term invariant under row+=16 (8m & 3 == 0)
  const int lr = lane & 15, s = lane >> 4;
  const int rdswz = ((s ^ ((lr >> 1) & 3)) << 3);          // element offset
  const int wm = w >> 1, wn = w & 1;
  const int arow = wm * 64 + lr;
  const int brow = wn * 64 + lr;

  f32x4 accg[4][4] = {};
  f32x4 accu[4][4] = {};

  STAGE_A(0); STAGE_B(0);
  STAGE_A(1); STAGE_B(1);
  STAGE_A(2); STAGE_B(2);

  const int NT = HID / BK;   // 32
#pragma unroll 4
  for (int kt = 0; kt < NT; ++kt) {
    const int b = kt & 3;
    // 4 loads/tile; tiles kt+1,kt+2 in flight = 8 -> tile kt landed
    asm volatile("s_waitcnt vmcnt(8)" ::: "memory");
    __builtin_amdgcn_s_barrier();

    const unsigned short* ab = As  + b * (UBM * BK);
    const unsigned short* gb = Bgs + b * (UBN * BK);
    const unsigned short* ub = Bus + b * (UBN * BK);

    bf16x8 af[4], bgf[4];
#pragma unroll
    for (int m = 0; m < 4; ++m)
      af[m] = *(const bf16x8*)(ab + (arow + m * 16) * BK + rdswz);
#pragma unroll
    for (int n = 0; n < 4; ++n)
      bgf[n] = *(const bf16x8*)(gb + (brow + n * 16) * BK + rdswz);
    if (kt + 3 < NT) STAGE_A(kt + 3);    // into buf[(kt-1)&3]: freed (reads done pre-barrier)
    __builtin_amdgcn_s_barrier();

    __builtin_amdgcn_s_setprio(1);
#pragma unroll
    for (int m = 0; m < 4; ++m)
#pragma unroll
      for (int n = 0; n < 4; ++n)
        accg[m][n] = __builtin_amdgcn_mfma_f32_16x16x32_bf16(af[m], bgf[n], accg[m][n], 0, 0, 0);
    __builtin_amdgcn_s_setprio(0);

    bf16x8 buf_[4];
#pragma unroll
    for (int n = 0; n < 4; ++n)
      buf_[n] = *(const bf16x8*)(ub + (brow + n * 16) * BK + rdswz);
    if (kt + 3 < NT) STAGE_B(kt + 3);
    __builtin_amdgcn_s_barrier();

    __builtin_amdgcn_s_setprio(1);
#pragma unroll
    for (int m = 0; m < 4; ++m)
#pragma unroll
      for (int n = 0; n < 4; ++n)
        accu[m][n] = __builtin_amdgcn_mfma_f32_16x16x32_bf16(af[m], buf_[n], accu[m][n], 0, 0, 0);
    __builtin_amdgcn_s_setprio(0);
  }

  const int crb = (lane >> 4) * 4, cc = lane & 15;
#pragma unroll
  for (int m = 0; m < 4; ++m)
#pragma unroll
    for (int n = 0; n < 4; ++n)
#pragma unroll
      for (int r = 0; r < 4; ++r) {
        int lrow = wm * 64 + m * 16 + crb + r;
        int grow = mblk * UBM + lrow;
        if (grow < cnt) {
          size_t a = (size_t)off + grow;
          float g = accg[m][n][r];
          float u = accu[m][n][r];
          float sg = g / (1.0f + __expf(-g));   // silu
          hbuf[a * FFD + (n0 + wn * 64 + n * 16 + cc)] = f2bf(sg * u);
        }
      }
}

#define DBM 128
#define DBN 256
// down LDS elems per buffer: A 128*32=4096, B 256*32=8192

__global__ __launch_bounds__(512, 2) void moe_down_kernel(
    const unsigned short* __restrict__ hb,    // [A][F] bf16
    const unsigned short* __restrict__ WdT,   // [E][H][F] bf16
    const int* __restrict__ counts, const int* __restrict__ offsets,
    float* __restrict__ ypart)                // [A][H] fp32
{
  const int e = blockIdx.x >> 6;
  const int mblk = blockIdx.x & 63;
  const int cnt = counts[e];
  if (mblk * DBM >= cnt) return;
  const int off = offsets[e];
  const int n0 = blockIdx.y * DBN;

  __shared__ __align__(16) unsigned short As[4 * DBM * BK];   // 32 KiB
  __shared__ __align__(16) unsigned short Bs[4 * DBN * BK];   // 64 KiB

  const int tid = threadIdx.x;
  const int lane = tid & 63;
  const int w = tid >> 6;

  const int trow = tid >> 2;
  const int tcol = swz_col(tid);
  int arow_g = off + mblk * DBM + trow;
  if (arow_g > NASSIGN - 1) arow_g = NASSIGN - 1;
  const unsigned short* a_src  = hb + (size_t)arow_g * FFD + tcol;
  const unsigned short* b_src0 = WdT + ((size_t)e * HID + n0 + trow) * FFD + tcol;
  const unsigned short* b_src1 = WdT + ((size_t)e * HID + n0 + 128 + trow) * FFD + tcol;

  auto STAGE = [&](int kt) {
    const int b = kt & 3, k0 = kt * BK;
    gload16(a_src  + k0, As + b * (DBM * BK) + tid * 8);
    gload16(b_src0 + k0, Bs + b * (DBN * BK) + tid * 8);
    gload16(b_src1 + k0, Bs + b * (DBN * BK) + 4096 + tid * 8);
  };

  const int lr = lane & 15, s = lane >> 4;
  const int rdswz = ((s ^ ((lr >> 1) & 3)) << 3);
  const int wm = w >> 2, wn = w & 3;
  const int arow = wm * 64 + lr;
  const int brow = wn * 64 + lr;

  f32x4 acc[4][4] = {};

  STAGE(0); STAGE(1); STAGE(2);

  const int NT = FFD / BK;   // 128
#pragma unroll 4
  for (int kt = 0; kt < NT; ++kt) {
    const int b = kt & 3;
    // 3 loads/tile; tiles kt+1,kt+2 in flight = 6 -> tile kt landed
    asm volatile("s_waitcnt vmcnt(6)" ::: "memory");
    __builtin_amdgcn_s_barrier();

    const unsigned short* ab = As + b * (DBM * BK);
    const unsigned short* bb = Bs + b * (DBN * BK);

    bf16x8 af[4], bf_[4];
#pragma unroll
    for (int m = 0; m < 4; ++m)
      af[m] = *(const bf16x8*)(ab + (arow + m * 16) * BK + rdswz);
#pragma unroll
    for (int n = 0; n < 4; ++n)
      bf_[n] = *(const bf16x8*)(bb + (brow + n * 16) * BK + rdswz);
    if (kt + 3 < NT) STAGE(kt + 3);
    __builtin_amdgcn_s_barrier();

    __builtin_amdgcn_s_setprio(1);
#pragma unroll
    for (int m = 0; m < 4; ++m)
#pragma unroll
      for (int n = 0; n < 4; ++n)
        acc[m][n] = __builtin_amdgcn_mfma_f32_16x16x32_bf16(af[m], bf_[n], acc[m][n], 0, 0, 0);
    __builtin_amdgcn_s_setprio(0);
  }

  const int crb = (lane >> 4) * 4, cc = lane & 15;
#pragma unroll
  for (int m = 0; m < 4; ++m)
#pragma unroll
    for (int n = 0; n < 4; ++n)
#pragma unroll
      for (int r = 0; r < 4; ++r) {
        int lrow = wm * 64 + m * 16 + crb + r;
        int grow = mblk * DBM + lrow;
        if (grow < cnt)
          ypart[((size_t)off + grow) * HID + (n0 + wn * 64 + n * 16 + cc)] = acc[m][n][r];
      }
}

__global__ void combine_kernel(const float* __restrict__ ypart,
                               const int* __restrict__ asn_of,
                               const float* __restrict__ wt_of,
                               float* __restrict__ y) {
  const int t = blockIdx.x;
  const int a0 = asn_of[t * 2], a1 = asn_of[t * 2 + 1];
  const float w0 = wt_of[a0], w1 = wt_of[a1];
  const int c = threadIdx.x * 4;
  float4 p0 = *(const float4*)&ypart[(size_t)a0 * HID + c];
  float4 p1 = *(const float4*)&ypart[(size_t)a1 * HID + c];
  float4 r;
  r.x = w0 * p0.x + w1 * p1.x;
  r.y = w0 * p0.y + w1 * p1.y;
  r.z = w0 * p0.z + w1 * p1.z;
  r.w = w0 * p0.w + w1 * p1.w;
  *(float4*)&y[(size_t)t * HID + c] = r;
}

// ---------------- launch ----------------

extern "C" void kernel_launch(void* const* d_in, const int* in_sizes, int n_in,
                              void* d_out, int out_size, void* d_ws, size_t ws_size,
                              hipStream_t stream) {
  const float* x  = (const float*)d_in[0];
  const float* gw = (const float*)d_in[1];
  const float* gb = (const float*)d_in[2];
  const float* Wg = (const float*)d_in[3];
  const float* Wu = (const float*)d_in[4];
  const float* Wd = (const float*)d_in[5];
  float* out = (float*)d_out;
  float* logits = out + (size_t)TTOK * HID;

  char* ws = (char*)d_ws;
  size_t o = 0;
  auto carve = [&](size_t b) { char* p = ws + o; o += (b + 255) & ~(size_t)255; return p; };
  int*   counts  = (int*)carve(NEXP * 4);
  int*   offsets = (int*)carve(NEXP * 4);
  int*   te      = (int*)carve((size_t)TTOK * 2 * 4);
  int*   tp      = (int*)carve((size_t)TTOK * 2 * 4);
  float* tw      = (float*)carve((size_t)TTOK * 2 * 4);
  int*   tok_of  = (int*)carve((size_t)NASSIGN * 4);
  float* wt_of   = (float*)carve((size_t)NASSIGN * 4);
  int*   asn_of  = (int*)carve((size_t)TTOK * 2 * 4);
  unsigned short* xb  = (unsigned short*)carve((size_t)TTOK * HID * 2);
  unsigned short* WgT = (unsigned short*)carve((size_t)NEXP * FFD * HID * 2);
  unsigned short* WuT = (unsigned short*)carve((size_t)NEXP * FFD * HID * 2);
  unsigned short* WdT = (unsigned short*)carve((size_t)NEXP * HID * FFD * 2);
  unsigned short* hb  = (unsigned short*)carve((size_t)NASSIGN * FFD * 2);
  float* ypart        = (float*)carve((size_t)NASSIGN * HID * 4);
  (void)ws_size; (void)in_sizes; (void)n_in; (void)out_size;

  zero_counts_kernel<<<dim3(1), dim3(64), 0, stream>>>(counts);
  gate_kernel<<<dim3(TTOK / 4), dim3(256), 0, stream>>>(x, gw, gb, logits, counts, te, tp, tw);
  scatter_kernel<<<dim3(1), dim3(256), 0, stream>>>(counts, offsets, te, tp, tw, tok_of, wt_of, asn_of);
  convert_x_kernel<<<dim3((TTOK * HID) / 2048), dim3(256), 0, stream>>>(x, xb);
  transpose_cvt_kernel<<<dim3(FFD / 32, HID / 32, NEXP), dim3(32, 8), 0, stream>>>(Wg, WgT, HID, FFD);
  transpose_cvt_kernel<<<dim3(FFD / 32, HID / 32, NEXP), dim3(32, 8), 0, stream>>>(Wu, WuT, HID, FFD);
  transpose_cvt_kernel<<<dim3(HID / 32, FFD / 32, NEXP), dim3(32, 8), 0, stream>>>(Wd, WdT, FFD, HID);
  moe_up_kernel<<<dim3(NEXP * 32, FFD / UBN), dim3(512), 0, stream>>>(xb, WgT, WuT, counts, offsets, tok_of, hb);
  moe_down_kernel<<<dim3(NEXP * 64, HID / DBN), dim3(512), 0, stream>>>(hb, WdT, counts, offsets, ypart);
  combine_kernel<<<dim3(TTOK), dim3(256), 0, stream>>>(ypart, asn_of, wt_of, out);
}

// Round 4
// 1084.470 us; speedup vs baseline: 1.7259x; 1.7259x over previous
//
#include <hip/hip_runtime.h>
#include <cstdint>

#define TTOK 8192
#define HID  1024
#define FFD  4096
#define NEXP 8
#define NASSIGN 16384   // TTOK * 2

typedef __attribute__((ext_vector_type(8))) short bf16x8;
typedef __attribute__((ext_vector_type(4))) float f32x4;

__device__ __forceinline__ unsigned short f2bf(float f) {
  unsigned int u = __builtin_bit_cast(unsigned int, f);
  u += 0x7FFFu + ((u >> 16) & 1u);           // RNE
  return (unsigned short)(u >> 16);
}

__device__ __forceinline__ void gload16(const unsigned short* g, unsigned short* l) {
  __builtin_amdgcn_global_load_lds(
      (const __attribute__((address_space(1))) unsigned int*)g,
      (__attribute__((address_space(3))) unsigned int*)l, 16, 0, 0);
}

// swizzled source column (elements) for staging thread t: slot ^= (row>>1)&3,
// row = t>>2 so (row>>1)&3 = (t>>3)&3. Involution; matched by read-side XOR.
__device__ __forceinline__ int swz_col(int t) {
  return (((t & 3) ^ ((t >> 3) & 3)) << 3);
}

// ---------------- routing ----------------

__global__ void zero_counts_kernel(int* counts) {
  if (threadIdx.x < NEXP) counts[threadIdx.x] = 0;
}

__global__ void gate_kernel(const float* __restrict__ x,
                            const float* __restrict__ gw,
                            const float* __restrict__ gb,
                            float* __restrict__ logits_out,
                            int* __restrict__ counts,
                            int* __restrict__ te, int* __restrict__ tp,
                            float* __restrict__ tw) {
  const int lane = threadIdx.x & 63;
  const int wib  = threadIdx.x >> 6;
  const int t = blockIdx.x * 4 + wib;
  const float* xr = x + (size_t)t * HID;

  float acc[NEXP];
#pragma unroll
  for (int e = 0; e < NEXP; ++e) acc[e] = 0.f;

#pragma unroll
  for (int i = 0; i < HID / 64; ++i) {
    int h = lane + 64 * i;
    float xv = xr[h];
    const float* g = gw + h * NEXP;
#pragma unroll
    for (int e = 0; e < NEXP; ++e) acc[e] += xv * g[e];
  }
#pragma unroll
  for (int off = 32; off; off >>= 1)
#pragma unroll
    for (int e = 0; e < NEXP; ++e) acc[e] += __shfl_xor(acc[e], off);
#pragma unroll
  for (int e = 0; e < NEXP; ++e) acc[e] += gb[e];

  if (lane < NEXP) logits_out[(size_t)t * NEXP + lane] = acc[lane];

  if (lane == 0) {
    int e0 = 0; float v0 = acc[0];
#pragma unroll
    for (int e = 1; e < NEXP; ++e) if (acc[e] > v0) { v0 = acc[e]; e0 = e; }
    int e1 = -1; float v1 = -3.4e38f;
#pragma unroll
    for (int e = 0; e < NEXP; ++e) if (e != e0 && acc[e] > v1) { v1 = acc[e]; e1 = e; }
    float s = __expf(v1 - v0);         // v1 <= v0
    float w0 = 1.f / (1.f + s);
    float w1 = s * w0;
    int p0 = atomicAdd(&counts[e0], 1);
    int p1 = atomicAdd(&counts[e1], 1);
    te[t * 2] = e0; te[t * 2 + 1] = e1;
    tp[t * 2] = p0; tp[t * 2 + 1] = p1;
    tw[t * 2] = w0; tw[t * 2 + 1] = w1;
  }
}

__global__ void scatter_kernel(const int* __restrict__ counts, int* __restrict__ offsets,
                               const int* __restrict__ te, const int* __restrict__ tp,
                               const float* __restrict__ tw,
                               int* __restrict__ tok_of, float* __restrict__ wt_of,
                               int* __restrict__ asn_of) {
  __shared__ int offs[NEXP];
  if (threadIdx.x == 0) {
    int run = 0;
    for (int e = 0; e < NEXP; ++e) { offs[e] = run; offsets[e] = run; run += counts[e]; }
  }
  __syncthreads();
  for (int t = threadIdx.x; t < TTOK; t += blockDim.x) {
#pragma unroll
    for (int j = 0; j < 2; ++j) {
      int e = te[t * 2 + j];
      int a = offs[e] + tp[t * 2 + j];
      tok_of[a] = t;
      wt_of[a] = tw[t * 2 + j];
      asn_of[t * 2 + j] = a;
    }
  }
}

// ---------------- dtype prep ----------------

__global__ void convert_x_kernel(const float* __restrict__ x, unsigned short* __restrict__ xb) {
  size_t i = ((size_t)blockIdx.x * 256 + threadIdx.x) * 8;
  float4 a = *(const float4*)(x + i);
  float4 b = *(const float4*)(x + i + 4);
  union { unsigned short us[8]; uint4 v; } u;
  u.us[0] = f2bf(a.x); u.us[1] = f2bf(a.y); u.us[2] = f2bf(a.z); u.us[3] = f2bf(a.w);
  u.us[4] = f2bf(b.x); u.us[5] = f2bf(b.y); u.us[6] = f2bf(b.z); u.us[7] = f2bf(b.w);
  *(uint4*)(xb + i) = u.v;
}

// src [z][R][C] fp32 -> dst [z][C][R] bf16
__global__ void transpose_cvt_kernel(const float* __restrict__ src,
                                     unsigned short* __restrict__ dst, int R, int C) {
  __shared__ float tile[32][33];
  const int r0 = blockIdx.y * 32, c0 = blockIdx.x * 32;
  const size_t base = (size_t)blockIdx.z * R * C;
  src += base; dst += base;
#pragma unroll
  for (int i = threadIdx.y; i < 32; i += 8)
    tile[i][threadIdx.x] = src[(size_t)(r0 + i) * C + c0 + threadIdx.x];
  __syncthreads();
#pragma unroll
  for (int i = threadIdx.y; i < 32; i += 8)
    dst[(size_t)(c0 + i) * R + r0 + threadIdx.x] = f2bf(tile[threadIdx.x][i]);
}

// ---------------- expert GEMMs ----------------
// Deep-pipelined (4-buffer ring, counted vmcnt, never drain-0 in loop),
// LDS XOR-swizzle via pre-swizzled global source + swizzled ds_read,
// s_setprio(1) around MFMA clusters. 512 threads / 8 waves / 1 block/CU.
// CRITICAL: e = blockIdx.x & 7 pins expert e to XCD e (consecutive blockIdx
// round-robin XCDs) -> each expert's weight panels live in ONE XCD L2.
// Round-3's e = bid>>5 decode broke this and multiplied weight fetch ~8x.

#define UBM 256
#define UBN 128
#define BK  32
// up LDS elems per buffer: A 256*32=8192, Bg/Bu 128*32=4096

__global__ __launch_bounds__(512, 2) void moe_up_kernel(
    const unsigned short* __restrict__ xb,    // [T][H] bf16
    const unsigned short* __restrict__ WgT,   // [E][F][H] bf16
    const unsigned short* __restrict__ WuT,   // [E][F][H] bf16
    const int* __restrict__ counts, const int* __restrict__ offsets,
    const int* __restrict__ tok_of,
    unsigned short* __restrict__ hbuf)        // [A][F] bf16
{
  const int e = blockIdx.x & 7;               // expert <-> XCD affinity
  const int mblk = blockIdx.x >> 3;
  const int cnt = counts[e];
  if (mblk * UBM >= cnt) return;
  const int off = offsets[e];
  const int n0 = blockIdx.y * UBN;

  __shared__ __align__(16) unsigned short As[4 * UBM * BK];    // 64 KiB
  __shared__ __align__(16) unsigned short Bgs[4 * UBN * BK];   // 32 KiB
  __shared__ __align__(16) unsigned short Bus[4 * UBN * BK];   // 32 KiB
  __shared__ int toks[UBM];

  const int tid = threadIdx.x;
  const int lane = tid & 63;
  const int w = tid >> 6;

  for (int i = tid; i < UBM; i += 512) {
    int a = off + mblk * UBM + i;
    if (a > NASSIGN - 1) a = NASSIGN - 1;
    toks[i] = tok_of[a];
  }
  __syncthreads();

  // staging source pointers (per thread, pre-swizzled column)
  const int trow = tid >> 2;
  const int tcol = swz_col(tid);
  const unsigned short* a_src0 = xb + (size_t)toks[trow] * HID + tcol;
  const unsigned short* a_src1 = xb + (size_t)toks[128 + trow] * HID + tcol;
  const unsigned short* bg_src = WgT + ((size_t)e * FFD + n0 + trow) * HID + tcol;
  const unsigned short* bu_src = WuT + ((size_t)e * FFD + n0 + trow) * HID + tcol;

  auto STAGE_A = [&](int kt) {
    const int b = kt & 3, k0 = kt * BK;
    gload16(a_src0 + k0, As + b * (UBM * BK) + tid * 8);
    gload16(a_src1 + k0, As + b * (UBM * BK) + 4096 + tid * 8);
  };
  auto STAGE_B = [&](int kt) {
    const int b = kt & 3, k0 = kt * BK;
    gload16(bg_src + k0, Bgs + b * (UBN * BK) + tid * 8);
    gload16(bu_src + k0, Bus + b * (UBN * BK) + tid * 8);
  };

  // read-side constants: XOR term invariant under row+=16 (8m & 3 == 0)
  const int lr = lane & 15, s = lane >> 4;
  const int rdswz = ((s ^ ((lr >> 1) & 3)) << 3);          // element offset
  const int wm = w >> 1, wn = w & 1;
  const int arow = wm * 64 + lr;
  const int brow = wn * 64 + lr;

  f32x4 accg[4][4] = {};
  f32x4 accu[4][4] = {};

  STAGE_A(0); STAGE_B(0);
  STAGE_A(1); STAGE_B(1);
  STAGE_A(2); STAGE_B(2);

  const int NT = HID / BK;   // 32
#pragma unroll 4
  for (int kt = 0; kt < NT; ++kt) {
    const int b = kt & 3;
    // 4 loads/tile; tiles kt+1,kt+2 in flight = 8 -> tile kt landed
    asm volatile("s_waitcnt vmcnt(8)" ::: "memory");
    __builtin_amdgcn_s_barrier();

    const unsigned short* ab = As  + b * (UBM * BK);
    const unsigned short* gb = Bgs + b * (UBN * BK);
    const unsigned short* ub = Bus + b * (UBN * BK);

    bf16x8 af[4], bgf[4];
#pragma unroll
    for (int m = 0; m < 4; ++m)
      af[m] = *(const bf16x8*)(ab + (arow + m * 16) * BK + rdswz);
#pragma unroll
    for (int n = 0; n < 4; ++n)
      bgf[n] = *(const bf16x8*)(gb + (brow + n * 16) * BK + rdswz);
    if (kt + 3 < NT) STAGE_A(kt + 3);    // into buf[(kt-1)&3]: freed (reads done pre-barrier)
    __builtin_amdgcn_s_barrier();

    __builtin_amdgcn_s_setprio(1);
#pragma unroll
    for (int m = 0; m < 4; ++m)
#pragma unroll
      for (int n = 0; n < 4; ++n)
        accg[m][n] = __builtin_amdgcn_mfma_f32_16x16x32_bf16(af[m], bgf[n], accg[m][n], 0, 0, 0);
    __builtin_amdgcn_s_setprio(0);

    bf16x8 buf_[4];
#pragma unroll
    for (int n = 0; n < 4; ++n)
      buf_[n] = *(const bf16x8*)(ub + (brow + n * 16) * BK + rdswz);
    if (kt + 3 < NT) STAGE_B(kt + 3);
    __builtin_amdgcn_s_barrier();

    __builtin_amdgcn_s_setprio(1);
#pragma unroll
    for (int m = 0; m < 4; ++m)
#pragma unroll
      for (int n = 0; n < 4; ++n)
        accu[m][n] = __builtin_amdgcn_mfma_f32_16x16x32_bf16(af[m], buf_[n], accu[m][n], 0, 0, 0);
    __builtin_amdgcn_s_setprio(0);
  }

  const int crb = (lane >> 4) * 4, cc = lane & 15;
#pragma unroll
  for (int m = 0; m < 4; ++m)
#pragma unroll
    for (int n = 0; n < 4; ++n)
#pragma unroll
      for (int r = 0; r < 4; ++r) {
        int lrow = wm * 64 + m * 16 + crb + r;
        int grow = mblk * UBM + lrow;
        if (grow < cnt) {
          size_t a = (size_t)off + grow;
          float g = accg[m][n][r];
          float u = accu[m][n][r];
          float sg = g / (1.0f + __expf(-g));   // silu
          hbuf[a * FFD + (n0 + wn * 64 + n * 16 + cc)] = f2bf(sg * u);
        }
      }
}

#define DBM 128
#define DBN 256
// down LDS elems per buffer: A 128*32=4096, B 256*32=8192

__global__ __launch_bounds__(512, 2) void moe_down_kernel(
    const unsigned short* __restrict__ hb,    // [A][F] bf16
    const unsigned short* __restrict__ WdT,   // [E][H][F] bf16
    const int* __restrict__ counts, const int* __restrict__ offsets,
    float* __restrict__ ypart)                // [A][H] fp32
{
  const int e = blockIdx.x & 7;               // expert <-> XCD affinity
  const int mblk = blockIdx.x >> 3;
  const int cnt = counts[e];
  if (mblk * DBM >= cnt) return;
  const int off = offsets[e];
  const int n0 = blockIdx.y * DBN;

  __shared__ __align__(16) unsigned short As[4 * DBM * BK];   // 32 KiB
  __shared__ __align__(16) unsigned short Bs[4 * DBN * BK];   // 64 KiB

  const int tid = threadIdx.x;
  const int lane = tid & 63;
  const int w = tid >> 6;

  const int trow = tid >> 2;
  const int tcol = swz_col(tid);
  int arow_g = off + mblk * DBM + trow;
  if (arow_g > NASSIGN - 1) arow_g = NASSIGN - 1;
  const unsigned short* a_src  = hb + (size_t)arow_g * FFD + tcol;
  const unsigned short* b_src0 = WdT + ((size_t)e * HID + n0 + trow) * FFD + tcol;
  const unsigned short* b_src1 = WdT + ((size_t)e * HID + n0 + 128 + trow) * FFD + tcol;

  auto STAGE = [&](int kt) {
    const int b = kt & 3, k0 = kt * BK;
    gload16(a_src  + k0, As + b * (DBM * BK) + tid * 8);
    gload16(b_src0 + k0, Bs + b * (DBN * BK) + tid * 8);
    gload16(b_src1 + k0, Bs + b * (DBN * BK) + 4096 + tid * 8);
  };

  const int lr = lane & 15, s = lane >> 4;
  const int rdswz = ((s ^ ((lr >> 1) & 3)) << 3);
  const int wm = w >> 2, wn = w & 3;
  const int arow = wm * 64 + lr;
  const int brow = wn * 64 + lr;

  f32x4 acc[4][4] = {};

  STAGE(0); STAGE(1); STAGE(2);

  const int NT = FFD / BK;   // 128
#pragma unroll 4
  for (int kt = 0; kt < NT; ++kt) {
    const int b = kt & 3;
    // 3 loads/tile; tiles kt+1,kt+2 in flight = 6 -> tile kt landed
    asm volatile("s_waitcnt vmcnt(6)" ::: "memory");
    __builtin_amdgcn_s_barrier();

    const unsigned short* ab = As + b * (DBM * BK);
    const unsigned short* bb = Bs + b * (DBN * BK);

    bf16x8 af[4], bf_[4];
#pragma unroll
    for (int m = 0; m < 4; ++m)
      af[m] = *(const bf16x8*)(ab + (arow + m * 16) * BK + rdswz);
#pragma unroll
    for (int n = 0; n < 4; ++n)
      bf_[n] = *(const bf16x8*)(bb + (brow + n * 16) * BK + rdswz);
    if (kt + 3 < NT) STAGE(kt + 3);
    __builtin_amdgcn_s_barrier();

    __builtin_amdgcn_s_setprio(1);
#pragma unroll
    for (int m = 0; m < 4; ++m)
#pragma unroll
      for (int n = 0; n < 4; ++n)
        acc[m][n] = __builtin_amdgcn_mfma_f32_16x16x32_bf16(af[m], bf_[n], acc[m][n], 0, 0, 0);
    __builtin_amdgcn_s_setprio(0);
  }

  const int crb = (lane >> 4) * 4, cc = lane & 15;
#pragma unroll
  for (int m = 0; m < 4; ++m)
#pragma unroll
    for (int n = 0; n < 4; ++n)
#pragma unroll
      for (int r = 0; r < 4; ++r) {
        int lrow = wm * 64 + m * 16 + crb + r;
        int grow = mblk * DBM + lrow;
        if (grow < cnt)
          ypart[((size_t)off + grow) * HID + (n0 + wn * 64 + n * 16 + cc)] = acc[m][n][r];
      }
}

__global__ void combine_kernel(const float* __restrict__ ypart,
                               const int* __restrict__ asn_of,
                               const float* __restrict__ wt_of,
                               float* __restrict__ y) {
  const int t = blockIdx.x;
  const int a0 = asn_of[t * 2], a1 = asn_of[t * 2 + 1];
  const float w0 = wt_of[a0], w1 = wt_of[a1];
  const int c = threadIdx.x * 4;
  float4 p0 = *(const float4*)&ypart[(size_t)a0 * HID + c];
  float4 p1 = *(const float4*)&ypart[(size_t)a1 * HID + c];
  float4 r;
  r.x = w0 * p0.x + w1 * p1.x;
  r.y = w0 * p0.y + w1 * p1.y;
  r.z = w0 * p0.z + w1 * p1.z;
  r.w = w0 * p0.w + w1 * p1.w;
  *(float4*)&y[(size_t)t * HID + c] = r;
}

// ---------------- launch ----------------

extern "C" void kernel_launch(void* const* d_in, const int* in_sizes, int n_in,
                              void* d_out, int out_size, void* d_ws, size_t ws_size,
                              hipStream_t stream) {
  const float* x  = (const float*)d_in[0];
  const float* gw = (const float*)d_in[1];
  const float* gb = (const float*)d_in[2];
  const float* Wg = (const float*)d_in[3];
  const float* Wu = (const float*)d_in[4];
  const float* Wd = (const float*)d_in[5];
  float* out = (float*)d_out;
  float* logits = out + (size_t)TTOK * HID;

  char* ws = (char*)d_ws;
  size_t o = 0;
  auto carve = [&](size_t b) { char* p = ws + o; o += (b + 255) & ~(size_t)255; return p; };
  int*   counts  = (int*)carve(NEXP * 4);
  int*   offsets = (int*)carve(NEXP * 4);
  int*   te      = (int*)carve((size_t)TTOK * 2 * 4);
  int*   tp      = (int*)carve((size_t)TTOK * 2 * 4);
  float* tw      = (float*)carve((size_t)TTOK * 2 * 4);
  int*   tok_of  = (int*)carve((size_t)NASSIGN * 4);
  float* wt_of   = (float*)carve((size_t)NASSIGN * 4);
  int*   asn_of  = (int*)carve((size_t)TTOK * 2 * 4);
  unsigned short* xb  = (unsigned short*)carve((size_t)TTOK * HID * 2);
  unsigned short* WgT = (unsigned short*)carve((size_t)NEXP * FFD * HID * 2);
  unsigned short* WuT = (unsigned short*)carve((size_t)NEXP * FFD * HID * 2);
  unsigned short* WdT = (unsigned short*)carve((size_t)NEXP * HID * FFD * 2);
  unsigned short* hb  = (unsigned short*)carve((size_t)NASSIGN * FFD * 2);
  float* ypart        = (float*)carve((size_t)NASSIGN * HID * 4);
  (void)ws_size; (void)in_sizes; (void)n_in; (void)out_size;

  zero_counts_kernel<<<dim3(1), dim3(64), 0, stream>>>(counts);
  gate_kernel<<<dim3(TTOK / 4), dim3(256), 0, stream>>>(x, gw, gb, logits, counts, te, tp, tw);
  scatter_kernel<<<dim3(1), dim3(256), 0, stream>>>(counts, offsets, te, tp, tw, tok_of, wt_of, asn_of);
  convert_x_kernel<<<dim3((TTOK * HID) / 2048), dim3(256), 0, stream>>>(x, xb);
  transpose_cvt_kernel<<<dim3(FFD / 32, HID / 32, NEXP), dim3(32, 8), 0, stream>>>(Wg, WgT, HID, FFD);
  transpose_cvt_kernel<<<dim3(FFD / 32, HID / 32, NEXP), dim3(32, 8), 0, stream>>>(Wu, WuT, HID, FFD);
  transpose_cvt_kernel<<<dim3(HID / 32, FFD / 32, NEXP), dim3(32, 8), 0, stream>>>(Wd, WdT, FFD, HID);
  moe_up_kernel<<<dim3(NEXP * 32, FFD / UBN), dim3(512), 0, stream>>>(xb, WgT, WuT, counts, offsets, tok_of, hb);
  moe_down_kernel<<<dim3(NEXP * 64, HID / DBN), dim3(512), 0, stream>>>(hb, WdT, counts, offsets, ypart);
  combine_kernel<<<dim3(TTOK), dim3(256), 0, stream>>>(ypart, asn_of, wt_of, out);
}